// Round 3
// 456.346 us; speedup vs baseline: 1.0210x; 1.0210x over previous
//
#include <hip/hip_runtime.h>

// HyperConnections fused kernel, v4.
// out[(b*S+s)*T+t, d] = res[...] + c[s] * rmsnorm(sum_s h_pre[s]*res[...])[d]
// where c[s] = sum_r Sinkhorn(exp(H_res))[s][r] * 2*sigmoid(H_post[r]).
//
// v4 = v3 with the nontemporal accesses on a native ext_vector_type(4)
// (clang's __builtin_nontemporal_* rejects HIP_vector_type<float,4>).
//
// Design (vs 466-us v1 baseline):
//  - Sinkhorn + all sigmoids hoisted to a 1-block precompute kernel writing
//    a module-owned __device__ global (8 floats). v1 re-ran a ~2000-cycle
//    serial Sinkhorn on thread 0 of EVERY block behind the block barrier
//    (16384 blocks), stalling the streaming waves.
//  - Hot kernel reads the 8 coefficients as uniform loads (L2-resident).
//  - Nontemporal load/store on res/out (zero-reuse streams); w stays cached.

#define S_ 4
#define T_ 4096
#define D_ 1024
#define NITER_ 20
#define EPSF_ 1e-5f

typedef float f32x4 __attribute__((ext_vector_type(4)));

__device__ float g_coef[8];   // [0..3] = h_pre[s], [4..7] = c[s]

__global__ void hyperconn_coeff(const float* __restrict__ hpre_l,
                                const float* __restrict__ hpost_l,
                                const float* __restrict__ hres)
{
    if (threadIdx.x != 0) return;

    float M[S_][S_];
    #pragma unroll
    for (int i = 0; i < S_; ++i)
        #pragma unroll
        for (int j = 0; j < S_; ++j)
            M[i][j] = __expf(hres[i * S_ + j]);

    for (int it = 0; it < NITER_; ++it) {
        #pragma unroll
        for (int i = 0; i < S_; ++i) {
            float inv = 1.0f / (M[i][0] + M[i][1] + M[i][2] + M[i][3] + EPSF_);
            M[i][0] *= inv; M[i][1] *= inv; M[i][2] *= inv; M[i][3] *= inv;
        }
        #pragma unroll
        for (int j = 0; j < S_; ++j) {
            float inv = 1.0f / (M[0][j] + M[1][j] + M[2][j] + M[3][j] + EPSF_);
            M[0][j] *= inv; M[1][j] *= inv; M[2][j] *= inv; M[3][j] *= inv;
        }
    }

    #pragma unroll
    for (int s = 0; s < S_; ++s) {
        g_coef[s] = 1.0f / (1.0f + __expf(-hpre_l[s]));    // h_pre[s]
        float c = 0.0f;
        #pragma unroll
        for (int r = 0; r < S_; ++r)
            c += M[s][r] * (2.0f / (1.0f + __expf(-hpost_l[r])));
        g_coef[S_ + s] = c;                                 // c[s]
    }
}

__global__ __launch_bounds__(256) void hyperconn_main(
    const float* __restrict__ res,
    const float* __restrict__ w,
    float* __restrict__ out)
{
    const int n   = blockIdx.x;          // n = b*T + t
    const int b   = n >> 12;             // T = 4096
    const int t   = n & (T_ - 1);
    const int tid = threadIdx.x;         // 256 threads, one f32x4 each

    __shared__ float s_part[4];          // one partial per wave (4 waves)

    // ---- coefficients: 8 uniform floats, L2-resident after coeff kernel ----
    const float h0 = g_coef[0], h1 = g_coef[1], h2 = g_coef[2], h3 = g_coef[3];
    const float c0 = g_coef[4], c1 = g_coef[5], c2 = g_coef[6], c3 = g_coef[7];

    const f32x4* res4 = reinterpret_cast<const f32x4*>(res);
    const f32x4* w4   = reinterpret_cast<const f32x4*>(w);
    f32x4*       out4 = reinterpret_cast<f32x4*>(out);

    const int    D4      = D_ / 4;                      // 256 f32x4 per row
    const size_t rowbase = (size_t)(b * S_) * T_ + t;   // row of stream 0
    const size_t sstride = (size_t)T_ * D4;             // f32x4s between streams

    // ---- load all 4 stream rows (each element read exactly once, no reuse) ----
    const size_t base = rowbase * D4 + tid;
    f32x4 r[S_];
    #pragma unroll
    for (int s = 0; s < S_; ++s)
        r[s] = __builtin_nontemporal_load(&res4[base + (size_t)s * sstride]);

    // ---- aggregate with h_pre ----
    f32x4 agg = h0 * r[0] + h1 * r[1] + h2 * r[2] + h3 * r[3];

    // ---- sum of squares over D=1024: wave shuffle + LDS across 4 waves ----
    float ssq = agg.x*agg.x + agg.y*agg.y + agg.z*agg.z + agg.w*agg.w;
    #pragma unroll
    for (int off = 32; off >= 1; off >>= 1)
        ssq += __shfl_down(ssq, off, 64);
    const int lane = tid & 63;
    const int wv   = tid >> 6;
    if (lane == 0) s_part[wv] = ssq;
    __syncthreads();
    const float tot     = s_part[0] + s_part[1] + s_part[2] + s_part[3];
    const float inv_rms = rsqrtf(tot * (1.0f / (float)D_) + EPSF_);

    // ---- normalize, scale by weight, distribute with c[s], add residual ----
    const f32x4 wt  = w4[tid];           // 4 KiB, reused by all blocks: keep cached
    const f32x4 nrm = agg * inv_rms * wt;

    const float cs[S_] = {c0, c1, c2, c3};
    #pragma unroll
    for (int s = 0; s < S_; ++s) {
        f32x4 o = r[s] + nrm * cs[s];
        __builtin_nontemporal_store(o, &out4[base + (size_t)s * sstride]);
    }
}

extern "C" void kernel_launch(void* const* d_in, const int* in_sizes, int n_in,
                              void* d_out, int out_size, void* d_ws, size_t ws_size,
                              hipStream_t stream) {
    const float* res     = (const float*)d_in[0];   // (B*S, T, D) f32
    const float* weight  = (const float*)d_in[1];   // (D,) f32
    const float* hpre_l  = (const float*)d_in[2];   // (S,) f32
    const float* hpost_l = (const float*)d_in[3];   // (S,) f32
    const float* hres    = (const float*)d_in[4];   // (S,S) f32
    float*       out     = (float*)d_out;

    hyperconn_coeff<<<1, 64, 0, stream>>>(hpre_l, hpost_l, hres);

    // grid = B*T rows; B*T = total_elems / (S*D)
    const int n_rows = in_sizes[0] / (S_ * D_);     // 16384 for B=4,T=4096
    hyperconn_main<<<n_rows, 256, 0, stream>>>(res, weight, out);
}

// Round 4
// 451.536 us; speedup vs baseline: 1.0319x; 1.0107x over previous
//
#include <hip/hip_runtime.h>

// HyperConnections fused kernel, v5.
// out[(b*S+s)*T+t, d] = res[...] + c[s] * rmsnorm(sum_s h_pre[s]*res[...])[d]
// where c[s] = sum_r Sinkhorn(exp(H_res))[s][r] * 2*sigmoid(H_post[r]).
//
// v5 changes vs v4 (456 us, main kernel ~125 us @ ~4.5 TB/s):
//  - Dropped ALL nontemporal hints: the proven-6.3-6.5 TB/s streams on this
//    chip (harness fills, float4 copy ubench) use plain loads/stores.
//  - Two consecutive t-rows per block: 2x memory-level parallelism per
//    thread, 2 independent shuffle-reduce chains (ILP), half the barriers
//    per byte. Grid 16384 -> 8192 blocks.
//  - Coefficients stay hoisted in a 1-block precompute kernel (v2 design);
//    uniform g_coef loads land in SGPRs.

#define S_ 4
#define T_ 4096
#define D_ 1024
#define NITER_ 20
#define EPSF_ 1e-5f

typedef float f32x4 __attribute__((ext_vector_type(4)));

__device__ float g_coef[8];   // [0..3] = h_pre[s], [4..7] = c[s]

__global__ void hyperconn_coeff(const float* __restrict__ hpre_l,
                                const float* __restrict__ hpost_l,
                                const float* __restrict__ hres)
{
    if (threadIdx.x != 0) return;

    float M[S_][S_];
    #pragma unroll
    for (int i = 0; i < S_; ++i)
        #pragma unroll
        for (int j = 0; j < S_; ++j)
            M[i][j] = __expf(hres[i * S_ + j]);

    for (int it = 0; it < NITER_; ++it) {
        #pragma unroll
        for (int i = 0; i < S_; ++i) {
            float inv = 1.0f / (M[i][0] + M[i][1] + M[i][2] + M[i][3] + EPSF_);
            M[i][0] *= inv; M[i][1] *= inv; M[i][2] *= inv; M[i][3] *= inv;
        }
        #pragma unroll
        for (int j = 0; j < S_; ++j) {
            float inv = 1.0f / (M[0][j] + M[1][j] + M[2][j] + M[3][j] + EPSF_);
            M[0][j] *= inv; M[1][j] *= inv; M[2][j] *= inv; M[3][j] *= inv;
        }
    }

    #pragma unroll
    for (int s = 0; s < S_; ++s) {
        g_coef[s] = 1.0f / (1.0f + __expf(-hpre_l[s]));    // h_pre[s]
        float c = 0.0f;
        #pragma unroll
        for (int r = 0; r < S_; ++r)
            c += M[s][r] * (2.0f / (1.0f + __expf(-hpost_l[r])));
        g_coef[S_ + s] = c;                                 // c[s]
    }
}

__global__ __launch_bounds__(256) void hyperconn_main(
    const float* __restrict__ res,
    const float* __restrict__ w,
    float* __restrict__ out)
{
    // Each block handles two consecutive rows n0 = 2*bid, n1 = n0+1.
    // n = b*T + t; n0 even => t0 even => t1 = t0+1 stays in the same b.
    const int n0  = blockIdx.x << 1;
    const int b   = n0 >> 12;            // T = 4096
    const int t0  = n0 & (T_ - 1);
    const int tid = threadIdx.x;         // 256 threads, one f32x4 per row each

    __shared__ float s_part[2][4];       // [row][wave]

    // ---- coefficients: 8 uniform floats (SGPR via uniform load) ----
    const float h0 = g_coef[0], h1 = g_coef[1], h2 = g_coef[2], h3 = g_coef[3];
    const float c0 = g_coef[4], c1 = g_coef[5], c2 = g_coef[6], c3 = g_coef[7];

    const f32x4* res4 = reinterpret_cast<const f32x4*>(res);
    const f32x4* w4   = reinterpret_cast<const f32x4*>(w);
    f32x4*       out4 = reinterpret_cast<f32x4*>(out);

    const int    D4      = D_ / 4;                       // 256 f32x4 per row
    const size_t base0   = ((size_t)(b * S_) * T_ + t0) * D4 + tid;
    const size_t sstride = (size_t)T_ * D4;              // f32x4s between streams

    // ---- load 4 stream rows x 2 t-positions (8 x 16B in flight) ----
    f32x4 r0[S_], r1[S_];
    #pragma unroll
    for (int s = 0; s < S_; ++s) {
        r0[s] = res4[base0 + (size_t)s * sstride];
        r1[s] = res4[base0 + (size_t)s * sstride + D4];
    }

    // ---- aggregate with h_pre ----
    f32x4 agg0 = h0 * r0[0] + h1 * r0[1] + h2 * r0[2] + h3 * r0[3];
    f32x4 agg1 = h0 * r1[0] + h1 * r1[1] + h2 * r1[2] + h3 * r1[3];

    // ---- sum of squares over D=1024: two interleaved shuffle chains ----
    float ssq0 = agg0.x*agg0.x + agg0.y*agg0.y + agg0.z*agg0.z + agg0.w*agg0.w;
    float ssq1 = agg1.x*agg1.x + agg1.y*agg1.y + agg1.z*agg1.z + agg1.w*agg1.w;
    #pragma unroll
    for (int off = 32; off >= 1; off >>= 1) {
        ssq0 += __shfl_down(ssq0, off, 64);
        ssq1 += __shfl_down(ssq1, off, 64);
    }
    const int lane = tid & 63;
    const int wv   = tid >> 6;
    if (lane == 0) { s_part[0][wv] = ssq0; s_part[1][wv] = ssq1; }
    __syncthreads();
    const float tot0 = s_part[0][0] + s_part[0][1] + s_part[0][2] + s_part[0][3];
    const float tot1 = s_part[1][0] + s_part[1][1] + s_part[1][2] + s_part[1][3];
    const float inv0 = rsqrtf(tot0 * (1.0f / (float)D_) + EPSF_);
    const float inv1 = rsqrtf(tot1 * (1.0f / (float)D_) + EPSF_);

    // ---- normalize, scale by weight, distribute with c[s], add residual ----
    const f32x4 wt   = w4[tid];          // 4 KiB, reused by all blocks
    const f32x4 nrm0 = agg0 * inv0 * wt;
    const f32x4 nrm1 = agg1 * inv1 * wt;

    const float cs[S_] = {c0, c1, c2, c3};
    #pragma unroll
    for (int s = 0; s < S_; ++s) {
        out4[base0 + (size_t)s * sstride]      = r0[s] + nrm0 * cs[s];
        out4[base0 + (size_t)s * sstride + D4] = r1[s] + nrm1 * cs[s];
    }
}

extern "C" void kernel_launch(void* const* d_in, const int* in_sizes, int n_in,
                              void* d_out, int out_size, void* d_ws, size_t ws_size,
                              hipStream_t stream) {
    const float* res     = (const float*)d_in[0];   // (B*S, T, D) f32
    const float* weight  = (const float*)d_in[1];   // (D,) f32
    const float* hpre_l  = (const float*)d_in[2];   // (S,) f32
    const float* hpost_l = (const float*)d_in[3];   // (S,) f32
    const float* hres    = (const float*)d_in[4];   // (S,S) f32
    float*       out     = (float*)d_out;

    hyperconn_coeff<<<1, 64, 0, stream>>>(hpre_l, hpost_l, hres);

    // grid = (B*T)/2 blocks, two t-rows per block
    const int n_rows = in_sizes[0] / (S_ * D_);     // 16384 for B=4,T=4096
    hyperconn_main<<<n_rows >> 1, 256, 0, stream>>>(res, weight, out);
}